// Round 5
// baseline (270.512 us; speedup 1.0000x reference)
//
#include <hip/hip_runtime.h>
#include <math.h>

// TM-score, single fused kernel, pred held in registers between phases.
// S=1024 samples, L=4096 residues, fp32. One block/sample, 512 threads,
// 8 residues/thread in 2 chunks of 2048 residues.
// Phase 1: coalesced global->LDS staging, unpack residues -> keep pred in
//          VGPRs, accumulate 16 covariance sums, pack mask bits.
// Solve:   every thread redundantly: fp64 H assembly + fp32 Jacobi on the
//          4x4 Horn matrix (proven absmax ~0 in R3).
// Phase 2: restage tru only (L2-hot), distances from register-held pred.

#define NS        1024
#define NL        4096
#define TPB       512
#define NCHUNK    2
#define CHUNK_RES (NL / NCHUNK)     // 2048
#define NWAVE     (TPB / 64)        // 8

__device__ __forceinline__ float waveReduceSum(float v) {
    #pragma unroll
    for (int off = 32; off > 0; off >>= 1)
        v += __shfl_down(v, off, 64);
    return v;
}

__global__ __launch_bounds__(TPB, 4) void tm_fused(
    const float* __restrict__ pred, const float* __restrict__ tru,
    const int* __restrict__ mask, float* __restrict__ out)
{
    const int s    = blockIdx.x;
    const int tid  = threadIdx.x;
    const int wave = tid >> 6, lane = tid & 63;
    const float* ps = pred + (size_t)s * NL * 3;

    __shared__ float ldsP[CHUNK_RES * 3];   // 24 KB
    __shared__ float ldsT[CHUNK_RES * 3];   // 24 KB
    __shared__ float sred[NWAVE][16];

    // pred residues held across phases: 8 per thread
    float px[8], py[8], pz[8];
    unsigned wmbits = 0;

    // acc: [0]=Lt [1..3]=St [4..6]=Sp [7..15]=C[i][j]=sum w*p_i*t_j
    float acc[16];
    #pragma unroll
    for (int i = 0; i < 16; ++i) acc[i] = 0.f;

    // ---------------- Phase 1: covariance sums ----------------
    #pragma unroll
    for (int k = 0; k < NCHUNK; ++k) {
        const int cbase = k * CHUNK_RES;
        const float4* gp = (const float4*)(ps  + (size_t)cbase * 3);
        const float4* gt = (const float4*)(tru + (size_t)cbase * 3);
        float4* lp = (float4*)ldsP;
        float4* lt = (float4*)ldsT;
        #pragma unroll
        for (int j = 0; j < 3; ++j) {          // coalesced: 1 KB/wave/instr
            const int idx = j * TPB + tid;
            lp[idx] = gp[idx];
            lt[idx] = gt[idx];
        }
        __syncthreads();

        const float4* rp = (const float4*)&ldsP[tid * 12];
        const float4* rt = (const float4*)&ldsT[tid * 12];
        const float4 q0 = rp[0], q1 = rp[1], q2 = rp[2];
        const float4 u0 = rt[0], u1 = rt[1], u2 = rt[2];
        const int4   mi = *(const int4*)(mask + cbase + tid * 4);

        const float lpx[4] = {q0.x, q0.w, q1.z, q2.y};
        const float lpy[4] = {q0.y, q1.x, q1.w, q2.z};
        const float lpz[4] = {q0.z, q1.y, q2.x, q2.w};
        const float ltx[4] = {u0.x, u0.w, u1.z, u2.y};
        const float lty[4] = {u0.y, u1.x, u1.w, u2.z};
        const float ltz[4] = {u0.z, u1.y, u2.x, u2.w};
        const int   im[4]  = {mi.x, mi.y, mi.z, mi.w};

        #pragma unroll
        for (int r = 0; r < 4; ++r) {
            const float w = im[r] ? 1.f : 0.f;
            if (im[r]) wmbits |= (1u << (k * 4 + r));
            px[k*4+r] = lpx[r]; py[k*4+r] = lpy[r]; pz[k*4+r] = lpz[r];
            const float wpx = w * lpx[r], wpy = w * lpy[r], wpz = w * lpz[r];
            acc[0] += w;
            acc[1] += w * ltx[r]; acc[2] += w * lty[r]; acc[3] += w * ltz[r];
            acc[4] += wpx; acc[5] += wpy; acc[6] += wpz;
            acc[7]  += wpx * ltx[r]; acc[8]  += wpx * lty[r]; acc[9]  += wpx * ltz[r];
            acc[10] += wpy * ltx[r]; acc[11] += wpy * lty[r]; acc[12] += wpy * ltz[r];
            acc[13] += wpz * ltx[r]; acc[14] += wpz * lty[r]; acc[15] += wpz * ltz[r];
        }
        __syncthreads();   // before next chunk overwrites LDS
    }

    #pragma unroll
    for (int i = 0; i < 16; ++i) {
        float r = waveReduceSum(acc[i]);
        if (lane == 0) sred[wave][i] = r;
    }
    __syncthreads();

    // ------- Solve (all threads, identical): fp64 H + fp32 Jacobi -------
    double S[16];
    #pragma unroll
    for (int i = 0; i < 16; ++i) {
        double t = 0.0;
        #pragma unroll
        for (int wv = 0; wv < NWAVE; ++wv) t += (double)sred[wv][i];
        S[i] = t;
    }

    const double Lt = S[0], invLt = 1.0 / Lt;
    const double tmxd = S[1]*invLt, tmyd = S[2]*invLt, tmzd = S[3]*invLt;
    const double pmxd = S[4]*invLt, pmyd = S[5]*invLt, pmzd = S[6]*invLt;

    float H[3][3];
    {
        const double Sp[3] = {S[4], S[5], S[6]};
        const double St[3] = {S[1], S[2], S[3]};
        #pragma unroll
        for (int i = 0; i < 3; ++i)
            #pragma unroll
            for (int j = 0; j < 3; ++j)
                H[i][j] = (float)((S[7 + i*3 + j] - Sp[i]*St[j]*invLt) * invLt);
    }

    const float Sxx=H[0][0], Sxy=H[0][1], Sxz=H[0][2];
    const float Syx=H[1][0], Syy=H[1][1], Syz=H[1][2];
    const float Szx=H[2][0], Szy=H[2][1], Szz=H[2][2];
    float A[4][4] = {
      { Sxx+Syy+Szz, Syz-Szy,      Szx-Sxz,      Sxy-Syx      },
      { Syz-Szy,     Sxx-Syy-Szz,  Sxy+Syx,      Szx+Sxz      },
      { Szx-Sxz,     Sxy+Syx,      Syy-Sxx-Szz,  Syz+Szy      },
      { Sxy-Syx,     Szx+Sxz,      Syz+Szy,      Szz-Sxx-Syy  }
    };
    float V[4][4] = {{1,0,0,0},{0,1,0,0},{0,0,1,0},{0,0,0,1}};

    for (int sweep = 0; sweep < 8; ++sweep) {
        for (int p = 0; p < 3; ++p) for (int q = p+1; q < 4; ++q) {
            const float apq = A[p][q];
            if (fabsf(apq) < 1e-30f) continue;
            const float tau = (A[q][q] - A[p][p]) / (2.0f * apq);
            const float tt  = (tau >= 0.0f ? 1.0f : -1.0f)
                              / (fabsf(tau) + sqrtf(1.0f + tau*tau));
            const float cc  = 1.0f / sqrtf(1.0f + tt*tt);
            const float sn  = tt * cc;
            #pragma unroll
            for (int m = 0; m < 4; ++m) {
                const float akp = A[m][p], akq = A[m][q];
                A[m][p] = cc*akp - sn*akq;
                A[m][q] = sn*akp + cc*akq;
            }
            #pragma unroll
            for (int m = 0; m < 4; ++m) {
                const float apk = A[p][m], aqk = A[q][m];
                A[p][m] = cc*apk - sn*aqk;
                A[q][m] = sn*apk + cc*aqk;
            }
            #pragma unroll
            for (int m = 0; m < 4; ++m) {
                const float vkp = V[m][p], vkq = V[m][q];
                V[m][p] = cc*vkp - sn*vkq;
                V[m][q] = sn*vkp + cc*vkq;
            }
        }
    }
    int imax = 0;
    #pragma unroll
    for (int i = 1; i < 4; ++i) if (A[i][i] > A[imax][imax]) imax = i;
    const float q0f = V[0][imax], qxf = V[1][imax], qyf = V[2][imax], qzf = V[3][imax];

    const float R00 = q0f*q0f+qxf*qxf-qyf*qyf-qzf*qzf;
    const float R01 = 2.0f*(qxf*qyf - q0f*qzf);
    const float R02 = 2.0f*(qxf*qzf + q0f*qyf);
    const float R10 = 2.0f*(qyf*qxf + q0f*qzf);
    const float R11 = q0f*q0f-qxf*qxf+qyf*qyf-qzf*qzf;
    const float R12 = 2.0f*(qyf*qzf - q0f*qxf);
    const float R20 = 2.0f*(qzf*qxf - q0f*qyf);
    const float R21 = 2.0f*(qzf*qyf + q0f*qxf);
    const float R22 = q0f*q0f-qxf*qxf-qyf*qyf+qzf*qzf;

    double d0 = (Lt <= 15.0) ? 0.5 : (1.24 * cbrt(Lt - 15.0) - 1.8);
    if (d0 < 0.5) d0 = 0.5;
    const float inv_d0sq = (float)(1.0 / (d0 * d0));
    const float invLtf   = (float)invLt;
    const float pmx = (float)pmxd, pmy = (float)pmyd, pmz = (float)pmzd;
    const float tmx = (float)tmxd, tmy = (float)tmyd, tmz = (float)tmzd;

    // ---------------- Phase 2: restage tru only; pred from regs ----------------
    float tacc = 0.f;
    #pragma unroll
    for (int k = 0; k < NCHUNK; ++k) {
        const int cbase = k * CHUNK_RES;
        const float4* gt = (const float4*)(tru + (size_t)cbase * 3);
        float4* lt = (float4*)ldsT;
        #pragma unroll
        for (int j = 0; j < 3; ++j) {
            const int idx = j * TPB + tid;
            lt[idx] = gt[idx];
        }
        __syncthreads();

        const float4* rt = (const float4*)&ldsT[tid * 12];
        const float4 u0 = rt[0], u1 = rt[1], u2 = rt[2];
        const float ltx[4] = {u0.x, u0.w, u1.z, u2.y};
        const float lty[4] = {u0.y, u1.x, u1.w, u2.z};
        const float ltz[4] = {u0.z, u1.y, u2.x, u2.w};

        #pragma unroll
        for (int r = 0; r < 4; ++r) {
            const float w = (wmbits >> (k * 4 + r)) & 1u ? 1.f : 0.f;
            const float vx = px[k*4+r] - pmx, vy = py[k*4+r] - pmy, vz = pz[k*4+r] - pmz;
            const float a0 = R00*vx + R01*vy + R02*vz + tmx - ltx[r];
            const float a1 = R10*vx + R11*vy + R12*vz + tmy - lty[r];
            const float a2 = R20*vx + R21*vy + R22*vz + tmz - ltz[r];
            const float dsq = a0*a0 + a1*a1 + a2*a2;
            tacc += w * __builtin_amdgcn_rcpf(1.0f + dsq * inv_d0sq);
        }
        __syncthreads();
    }
    tacc *= invLtf;

    float r = waveReduceSum(tacc);
    if (lane == 0) sred[wave][0] = r;
    __syncthreads();
    if (tid == 0) {
        float t = 0.f;
        #pragma unroll
        for (int wv = 0; wv < NWAVE; ++wv) t += sred[wv][0];
        out[s] = t;
    }
}

extern "C" void kernel_launch(void* const* d_in, const int* in_sizes, int n_in,
                              void* d_out, int out_size, void* d_ws, size_t ws_size,
                              hipStream_t stream) {
    const float* pred = (const float*)d_in[0];
    const float* tru  = (const float*)d_in[1];
    const int*   mask = (const int*)d_in[2];
    float* out = (float*)d_out;
    (void)d_ws; (void)ws_size;
    tm_fused<<<NS, TPB, 0, stream>>>(pred, tru, mask, out);
}

// Round 6
// 156.291 us; speedup vs baseline: 1.7308x; 1.7308x over previous
//
#include <hip/hip_runtime.h>
#include <math.h>

// TM-score, single fused kernel. S=1024 samples, L=4096 residues, fp32.
// One block/sample, 256 threads, 16 residues/thread in 4 chunks.
// Pred sample (48 KB) staged ONCE coalesced into LDS; both phases read it
// from LDS at 48 B/lane stride (conflict-free, verified R4). tru (48 KB,
// shared across blocks) read per-thread from global -> L2-hot. Mask bits
// cached in a register. Solve: per-thread redundant fp32 Jacobi on the 4x4
// Horn matrix (fp64 H assembly) -- proven absmax ~0.
// LDS ~48.3 KB -> 3 blocks/CU. No arrays held across the solve -> no spill.

#define NS   1024
#define NL   4096
#define TPB  256
#define NCHUNK 4
#define CHUNK_RES (NL / NCHUNK)   // 1024 residues/chunk, 4/thread

__device__ __forceinline__ float waveReduceSum(float v) {
    #pragma unroll
    for (int off = 32; off > 0; off >>= 1)
        v += __shfl_down(v, off, 64);
    return v;
}

__global__ __launch_bounds__(TPB, 4) void tm_fused(
    const float* __restrict__ pred, const float* __restrict__ tru,
    const int* __restrict__ mask, float* __restrict__ out)
{
    const int s    = blockIdx.x;
    const int tid  = threadIdx.x;
    const int wave = tid >> 6, lane = tid & 63;
    const float* ps = pred + (size_t)s * NL * 3;

    __shared__ float ldsP[NL * 3];          // 48 KB: whole pred sample
    __shared__ float sred[4][16];

    // ---- stage pred once, coalesced ----
    {
        const float4* gp = (const float4*)ps;
        float4* lp = (float4*)ldsP;
        #pragma unroll
        for (int j = 0; j < 12; ++j) {      // 3072 float4 / 256 threads
            const int idx = j * TPB + tid;
            lp[idx] = gp[idx];
        }
    }
    __syncthreads();

    // acc: [0]=Lt [1..3]=St [4..6]=Sp [7..15]=C[i][j]=sum w*p_i*t_j
    float acc[16];
    #pragma unroll
    for (int i = 0; i < 16; ++i) acc[i] = 0.f;
    unsigned wmbits = 0;

    // ---------------- Phase 1: covariance sums ----------------
    #pragma unroll
    for (int k = 0; k < NCHUNK; ++k) {
        const int rbase = k * CHUNK_RES + tid * 4;
        const float4* rp = (const float4*)&ldsP[rbase * 3];
        const float4* gt = (const float4*)(tru + (size_t)rbase * 3);
        const float4 q0 = rp[0], q1 = rp[1], q2 = rp[2];
        const float4 u0 = gt[0], u1 = gt[1], u2 = gt[2];
        const int4   mi = *(const int4*)(mask + rbase);

        const float px[4] = {q0.x, q0.w, q1.z, q2.y};
        const float py[4] = {q0.y, q1.x, q1.w, q2.z};
        const float pz[4] = {q0.z, q1.y, q2.x, q2.w};
        const float tx[4] = {u0.x, u0.w, u1.z, u2.y};
        const float ty[4] = {u0.y, u1.x, u1.w, u2.z};
        const float tz[4] = {u0.z, u1.y, u2.x, u2.w};
        const int   im[4] = {mi.x, mi.y, mi.z, mi.w};

        #pragma unroll
        for (int r = 0; r < 4; ++r) {
            const float w = im[r] ? 1.f : 0.f;
            if (im[r]) wmbits |= (1u << (k * 4 + r));
            const float wpx = w * px[r], wpy = w * py[r], wpz = w * pz[r];
            acc[0] += w;
            acc[1] += w * tx[r]; acc[2] += w * ty[r]; acc[3] += w * tz[r];
            acc[4] += wpx; acc[5] += wpy; acc[6] += wpz;
            acc[7]  += wpx * tx[r]; acc[8]  += wpx * ty[r]; acc[9]  += wpx * tz[r];
            acc[10] += wpy * tx[r]; acc[11] += wpy * ty[r]; acc[12] += wpy * tz[r];
            acc[13] += wpz * tx[r]; acc[14] += wpz * ty[r]; acc[15] += wpz * tz[r];
        }
    }

    #pragma unroll
    for (int i = 0; i < 16; ++i) {
        float r = waveReduceSum(acc[i]);
        if (lane == 0) sred[wave][i] = r;
    }
    __syncthreads();

    // ------- Solve (all threads, identical): fp64 H + fp32 Jacobi -------
    double S[16];
    #pragma unroll
    for (int i = 0; i < 16; ++i)
        S[i] = (double)sred[0][i] + (double)sred[1][i]
             + (double)sred[2][i] + (double)sred[3][i];

    const double Lt = S[0], invLt = 1.0 / Lt;
    const double tmxd = S[1]*invLt, tmyd = S[2]*invLt, tmzd = S[3]*invLt;
    const double pmxd = S[4]*invLt, pmyd = S[5]*invLt, pmzd = S[6]*invLt;

    float H[3][3];
    {
        const double Sp[3] = {S[4], S[5], S[6]};
        const double St[3] = {S[1], S[2], S[3]};
        #pragma unroll
        for (int i = 0; i < 3; ++i)
            #pragma unroll
            for (int j = 0; j < 3; ++j)
                H[i][j] = (float)((S[7 + i*3 + j] - Sp[i]*St[j]*invLt) * invLt);
    }

    const float Sxx=H[0][0], Sxy=H[0][1], Sxz=H[0][2];
    const float Syx=H[1][0], Syy=H[1][1], Syz=H[1][2];
    const float Szx=H[2][0], Szy=H[2][1], Szz=H[2][2];
    float A[4][4] = {
      { Sxx+Syy+Szz, Syz-Szy,      Szx-Sxz,      Sxy-Syx      },
      { Syz-Szy,     Sxx-Syy-Szz,  Sxy+Syx,      Szx+Sxz      },
      { Szx-Sxz,     Sxy+Syx,      Syy-Sxx-Szz,  Syz+Szy      },
      { Sxy-Syx,     Szx+Sxz,      Syz+Szy,      Szz-Sxx-Syy  }
    };
    float V[4][4] = {{1,0,0,0},{0,1,0,0},{0,0,1,0},{0,0,0,1}};

    for (int sweep = 0; sweep < 8; ++sweep) {
        for (int p = 0; p < 3; ++p) for (int q = p+1; q < 4; ++q) {
            const float apq = A[p][q];
            if (fabsf(apq) < 1e-30f) continue;
            const float tau = (A[q][q] - A[p][p]) / (2.0f * apq);
            const float tt  = (tau >= 0.0f ? 1.0f : -1.0f)
                              / (fabsf(tau) + sqrtf(1.0f + tau*tau));
            const float cc  = 1.0f / sqrtf(1.0f + tt*tt);
            const float sn  = tt * cc;
            #pragma unroll
            for (int m = 0; m < 4; ++m) {
                const float akp = A[m][p], akq = A[m][q];
                A[m][p] = cc*akp - sn*akq;
                A[m][q] = sn*akp + cc*akq;
            }
            #pragma unroll
            for (int m = 0; m < 4; ++m) {
                const float apk = A[p][m], aqk = A[q][m];
                A[p][m] = cc*apk - sn*aqk;
                A[q][m] = sn*apk + cc*aqk;
            }
            #pragma unroll
            for (int m = 0; m < 4; ++m) {
                const float vkp = V[m][p], vkq = V[m][q];
                V[m][p] = cc*vkp - sn*vkq;
                V[m][q] = sn*vkp + cc*vkq;
            }
        }
    }
    int imax = 0;
    #pragma unroll
    for (int i = 1; i < 4; ++i) if (A[i][i] > A[imax][imax]) imax = i;
    const float q0f = V[0][imax], qxf = V[1][imax], qyf = V[2][imax], qzf = V[3][imax];

    const float R00 = q0f*q0f+qxf*qxf-qyf*qyf-qzf*qzf;
    const float R01 = 2.0f*(qxf*qyf - q0f*qzf);
    const float R02 = 2.0f*(qxf*qzf + q0f*qyf);
    const float R10 = 2.0f*(qyf*qxf + q0f*qzf);
    const float R11 = q0f*q0f-qxf*qxf+qyf*qyf-qzf*qzf;
    const float R12 = 2.0f*(qyf*qzf - q0f*qxf);
    const float R20 = 2.0f*(qzf*qxf - q0f*qyf);
    const float R21 = 2.0f*(qzf*qyf + q0f*qxf);
    const float R22 = q0f*q0f-qxf*qxf-qyf*qyf+qzf*qzf;

    double d0 = (Lt <= 15.0) ? 0.5 : (1.24 * cbrt(Lt - 15.0) - 1.8);
    if (d0 < 0.5) d0 = 0.5;
    const float inv_d0sq = (float)(1.0 / (d0 * d0));
    const float invLtf   = (float)invLt;
    const float pmx = (float)pmxd, pmy = (float)pmyd, pmz = (float)pmzd;
    const float tmx = (float)tmxd, tmy = (float)tmyd, tmz = (float)tmzd;

    // ------- Phase 2: pred from LDS, tru from global (L2-hot) -------
    float tacc = 0.f;
    #pragma unroll
    for (int k = 0; k < NCHUNK; ++k) {
        const int rbase = k * CHUNK_RES + tid * 4;
        const float4* rp = (const float4*)&ldsP[rbase * 3];
        const float4* gt = (const float4*)(tru + (size_t)rbase * 3);
        const float4 q0 = rp[0], q1 = rp[1], q2 = rp[2];
        const float4 u0 = gt[0], u1 = gt[1], u2 = gt[2];

        const float px[4] = {q0.x, q0.w, q1.z, q2.y};
        const float py[4] = {q0.y, q1.x, q1.w, q2.z};
        const float pz[4] = {q0.z, q1.y, q2.x, q2.w};
        const float tx[4] = {u0.x, u0.w, u1.z, u2.y};
        const float ty[4] = {u0.y, u1.x, u1.w, u2.z};
        const float tz[4] = {u0.z, u1.y, u2.x, u2.w};

        #pragma unroll
        for (int r = 0; r < 4; ++r) {
            const float w = ((wmbits >> (k * 4 + r)) & 1u) ? 1.f : 0.f;
            const float vx = px[r] - pmx, vy = py[r] - pmy, vz = pz[r] - pmz;
            const float a0 = R00*vx + R01*vy + R02*vz + tmx - tx[r];
            const float a1 = R10*vx + R11*vy + R12*vz + tmy - ty[r];
            const float a2 = R20*vx + R21*vy + R22*vz + tmz - tz[r];
            const float dsq = a0*a0 + a1*a1 + a2*a2;
            tacc += w * __builtin_amdgcn_rcpf(1.0f + dsq * inv_d0sq);
        }
    }
    tacc *= invLtf;

    float r = waveReduceSum(tacc);
    if (lane == 0) sred[wave][0] = r;
    __syncthreads();
    if (tid == 0)
        out[s] = sred[0][0] + sred[1][0] + sred[2][0] + sred[3][0];
}

extern "C" void kernel_launch(void* const* d_in, const int* in_sizes, int n_in,
                              void* d_out, int out_size, void* d_ws, size_t ws_size,
                              hipStream_t stream) {
    const float* pred = (const float*)d_in[0];
    const float* tru  = (const float*)d_in[1];
    const int*   mask = (const int*)d_in[2];
    float* out = (float*)d_out;
    (void)d_ws; (void)ws_size;
    tm_fused<<<NS, TPB, 0, stream>>>(pred, tru, mask, out);
}